// Round 12
// baseline (166.564 us; speedup 1.0000x reference)
//
#include <hip/hip_runtime.h>
#include <hip/hip_bf16.h>

typedef unsigned short ushort_t;
typedef __attribute__((ext_vector_type(4))) float f32x4;
typedef __attribute__((ext_vector_type(8))) __bf16 bfrag;

#define MFMA16(a,b,c) __builtin_amdgcn_mfma_f32_16x16x32_bf16((a),(b),(c),0,0,0)

#define HID 768
#define NH 12
#define SEQ 4096
#define QSCALE 0.18033688011112042f  /* 0.125 * log2(e): folds 1/sqrt(64) and exp->exp2 */

// Per-wave drain of outstanding global_load_lds BEFORE a barrier.
// __syncthreads() alone does NOT guarantee another wave's LDS-DMA has landed:
// vmcnt is per-wave and the waitcnt pass only protects same-wave reads.
#define WAIT_VMCNT0() asm volatile("s_waitcnt vmcnt(0)" ::: "memory")
#define WAIT_VMCNT4() asm volatile("s_waitcnt vmcnt(4)" ::: "memory")

__device__ __forceinline__ unsigned short f2bf(float x) {
  union { float f; unsigned u; } v; v.f = x;
  unsigned r = v.u + 0x7fffu + ((v.u >> 16) & 1u);  // RTNE
  return (unsigned short)(r >> 16);
}

typedef const unsigned char __attribute__((address_space(1)))* gas1_t;
typedef unsigned char __attribute__((address_space(3)))* las3_t;
__device__ __forceinline__ void gload_lds16(const void* g, void* l) {
  __builtin_amdgcn_global_load_lds((gas1_t)(unsigned long long)g,
                                   (las3_t)(unsigned)(unsigned long long)l,
                                   16, 0, 0);
}

__device__ __forceinline__ f32x4 zero4() { f32x4 z = {0.f, 0.f, 0.f, 0.f}; return z; }

// ---------------------------------------------------------------- kernel 1
__global__ __launch_bounds__(256) void cvt_hidden(const float* __restrict__ hs,
                                                  ushort_t* __restrict__ A) {
  int i = blockIdx.x * 256 + threadIdx.x;
  float4 v = ((const float4*)hs)[i];
  ushort4 o;
  o.x = f2bf(v.x); o.y = f2bf(v.y); o.z = f2bf(v.z); o.w = f2bf(v.w);
  ((ushort4*)A)[i] = o;
}

// ---------------------------------------------------------------- kernel 2
__global__ __launch_bounds__(256) void transpose_w(const float* __restrict__ Wq,
                                                   const float* __restrict__ Wk,
                                                   const float* __restrict__ Wv,
                                                   ushort_t* __restrict__ Wt) {
  const int z = blockIdx.z;
  const float* W = (z == 0) ? Wq : ((z == 1) ? Wk : Wv);
  const int k0 = blockIdx.x * 64, n0 = blockIdx.y * 64;
  __shared__ float tile[64][65];
  const int t = threadIdx.x;
  const int c4 = (t & 15) * 4;
  const int r = t >> 4;
#pragma unroll
  for (int it = 0; it < 4; ++it) {
    int rr = r + it * 16;
    float4 v = *(const float4*)&W[(size_t)(k0 + rr) * HID + n0 + c4];
    tile[c4 + 0][rr] = v.x; tile[c4 + 1][rr] = v.y;
    tile[c4 + 2][rr] = v.z; tile[c4 + 3][rr] = v.w;
  }
  __syncthreads();
#pragma unroll
  for (int it = 0; it < 4; ++it) {
    int nl = r + it * 16;
    ushort4 o;
    o.x = f2bf(tile[nl][c4 + 0]); o.y = f2bf(tile[nl][c4 + 1]);
    o.z = f2bf(tile[nl][c4 + 2]); o.w = f2bf(tile[nl][c4 + 3]);
    *(ushort4*)&Wt[((size_t)z * HID + n0 + nl) * HID + k0 + c4] = o;
  }
}

// ---------------------------------------------------------------- kernel 3
// V epilogue stores k-columns permuted within each 32-block:
// V_true col (32K + 16A + 4G + B) stored at (32K + 8G + 4A + B), matching the
// natural in-register k-order of the attn P fragments.  Bijective, zero cost.
__global__ __launch_bounds__(256) void qkv_gemm(const ushort_t* __restrict__ A,
                                                const ushort_t* __restrict__ Wt,
                                                const float* __restrict__ bq,
                                                const float* __restrict__ bk,
                                                const float* __restrict__ bv,
                                                ushort_t* __restrict__ Qh,
                                                ushort_t* __restrict__ Kh,
                                                ushort_t* __restrict__ Vt) {
  __shared__ ushort_t Als[128 * 64];
  __shared__ ushort_t Bls[128 * 64];
  const int z = blockIdx.z;
  const int m0 = blockIdx.x * 128, n0 = blockIdx.y * 128;
  const ushort_t* Wz = Wt + (size_t)z * HID * HID;
  const float* bias = (z == 0) ? bq : ((z == 1) ? bk : bv);
  const int t = threadIdx.x, w = t >> 6, lane = t & 63;
  const int g = lane >> 4, qc = lane & 15;
  const int srow = lane >> 3, sch = lane & 7;
  const int wm = w >> 1, wn = w & 1;

  f32x4 acc[4][4];
#pragma unroll
  for (int mt = 0; mt < 4; ++mt)
#pragma unroll
    for (int nt = 0; nt < 4; ++nt) acc[mt][nt] = zero4();

  for (int kt = 0; kt < 12; ++kt) {
    const int k0 = kt * 64;
#pragma unroll
    for (int i = 0; i < 4; ++i) {
      int row = w * 32 + i * 8 + srow;
      int chA = sch ^ (srow & 7);
      gload_lds16(&A[(size_t)(m0 + row) * HID + k0 + chA * 8],
                  &Als[(w * 32 + i * 8) * 64]);
      gload_lds16(&Wz[(size_t)(n0 + row) * HID + k0 + chA * 8],
                  &Bls[(w * 32 + i * 8) * 64]);
    }
    WAIT_VMCNT0();     // all of THIS wave's DMA landed; barrier makes it global
    __syncthreads();
#pragma unroll
    for (int kk = 0; kk < 2; ++kk) {
      bfrag af[4], bf_[4];
#pragma unroll
      for (int mt = 0; mt < 4; ++mt) {
        int row = wm * 64 + mt * 16 + qc;
        af[mt] = *(const bfrag*)((const char*)Als + row * 128 +
                                 (((kk * 4 + g) ^ (qc & 7)) << 4));
      }
#pragma unroll
      for (int nt = 0; nt < 4; ++nt) {
        int row = wn * 64 + nt * 16 + qc;
        bf_[nt] = *(const bfrag*)((const char*)Bls + row * 128 +
                                  (((kk * 4 + g) ^ (qc & 7)) << 4));
      }
#pragma unroll
      for (int mt = 0; mt < 4; ++mt)
#pragma unroll
        for (int nt = 0; nt < 4; ++nt)
          acc[mt][nt] = MFMA16(af[mt], bf_[nt], acc[mt][nt]);
    }
    __syncthreads();
  }

#pragma unroll
  for (int mt = 0; mt < 4; ++mt) {
#pragma unroll
    for (int nt = 0; nt < 4; ++nt) {
      int n = n0 + wn * 64 + nt * 16 + qc;
      int head = n >> 6, d = n & 63;
      float bb = bias[n];
      int mB = m0 + wm * 64 + mt * 16 + 4 * g;
      int bidx = mB >> 12, s0 = mB & 4095;
      f32x4 a = acc[mt][nt];
      if (z == 2) {
        ushort4 o;
        o.x = f2bf(a[0] + bb); o.y = f2bf(a[1] + bb);
        o.z = f2bf(a[2] + bb); o.w = f2bf(a[3] + bb);
        // permuted storage column: (32K|16A|4G|B) -> (32K|8G|4A|B); B=0 here
        int scol = (s0 & ~31) | (((s0 >> 2) & 3) << 3) | (((s0 >> 4) & 1) << 2);
        *(ushort4*)&Vt[((size_t)((bidx * NH + head) * 64 + d)) * SEQ + scol] = o;
      } else {
        ushort_t* dst = (z == 0) ? Qh : Kh;
        float sc = (z == 0) ? QSCALE : 1.0f;
        size_t base = (size_t)(bidx * NH + head) * SEQ;
#pragma unroll
        for (int i = 0; i < 4; ++i)
          dst[(base + s0 + i) * 64 + d] = f2bf((a[i] + bb) * sc);
      }
    }
  }
}

// ---------------------------------------------------------------- kernel 4 helpers
__device__ __forceinline__ void stage_tile(const ushort_t* __restrict__ Kb,
                                           const ushort_t* __restrict__ Vb,
                                           ushort_t* Kd, ushort_t* Vd,
                                           int kb, const int* jr, const int* jc, int w) {
#pragma unroll
  for (int i = 0; i < 2; ++i) {
    gload_lds16(&Kb[(size_t)(kb + jr[i]) * 64 + jc[i] * 8], &Kd[(w * 128 + i * 64) * 8]);
    gload_lds16(&Vb[(size_t)jr[i] * SEQ + kb + jc[i] * 8], &Vd[(w * 128 + i * 64) * 8]);
  }
}

// QK^T for one tile -> raw scores st (consumed one iteration LATER: the wave
// issues these 16 MFMAs and moves on; results are never waited on this iter).
__device__ __forceinline__ void qk_tile(const ushort_t* Kc, const bfrag (&qv)[2][2],
                                        f32x4 (&st)[2][4], int g, int qc) {
  bfrag ak[4][2];
#pragma unroll
  for (int s = 0; s < 4; ++s) {
    const int r = s * 16 + qc;
    ak[s][0] = *(const bfrag*)&Kc[r * 64 + ((g ^ (qc & 7)) * 8)];
    ak[s][1] = *(const bfrag*)&Kc[r * 64 + (((4 + g) ^ (qc & 7)) * 8)];
  }
#pragma unroll
  for (int qf = 0; qf < 2; ++qf)
#pragma unroll
    for (int s = 0; s < 4; ++s) {
      f32x4 z = zero4();
      z = MFMA16(ak[s][0], qv[qf][0], z);
      st[qf][s] = MFMA16(ak[s][1], qv[qf][1], z);
    }
}

// exp2 + pack + l-accumulate + PV for one tile (scores computed last iter).
__device__ __forceinline__ void sm_pv_tile(const ushort_t* Vc, const f32x4 (&st)[2][4],
                                           f32x4 (&o)[2][4], f32x4 (&lacc)[2],
                                           bfrag ones, int g, int qc) {
  bfrag bp[2][2];
#pragma unroll
  for (int qf = 0; qf < 2; ++qf) {
#pragma unroll
    for (int i = 0; i < 4; ++i) {
      bp[qf][0][i]     = (__bf16)__builtin_amdgcn_exp2f(st[qf][0][i]);
      bp[qf][0][4 + i] = (__bf16)__builtin_amdgcn_exp2f(st[qf][1][i]);
      bp[qf][1][i]     = (__bf16)__builtin_amdgcn_exp2f(st[qf][2][i]);
      bp[qf][1][4 + i] = (__bf16)__builtin_amdgcn_exp2f(st[qf][3][i]);
    }
    lacc[qf] = MFMA16(ones, bp[qf][0], lacc[qf]);
    lacc[qf] = MFMA16(ones, bp[qf][1], lacc[qf]);
  }
#pragma unroll
  for (int kk = 0; kk < 2; ++kk)
#pragma unroll
    for (int dt = 0; dt < 4; ++dt) {
      bfrag av = *(const bfrag*)&Vc[(dt * 16 + qc) * 64 + (((kk * 4 + g) ^ (qc & 7)) * 8)];
      o[0][dt] = MFMA16(av, bp[0][kk], o[0][dt]);
      o[1][dt] = MFMA16(av, bp[1][kk], o[1][dt]);
    }
}

// ---------------------------------------------------------------- kernel 4
// Flash attention, no-max softmax, zero-shuffle P, CROSS-TILE PIPELINE.
// Rounds 9-11 showed the per-wave serial chain (~3830cyc/tile vs ~1300 of
// issue work) is the binding constraint: QK->exp2->PV latencies serialize.
// Fix (T15 mechanism): carry scores across iterations.  Iter t program
// order: stage(t+2) -> QK(t+1) [results consumed NEXT iter -> never waited
// on] -> exp2(st_t) [VALU, overlaps QK MFMAs in the pipe] -> PV(t).  The
// chain shrinks to exp2+PV; the matrix pipe becomes the binding resource.
// 3 LDS buffers rotate mod 3: iter t reads K[(t+1)%3], V[t%3], stages into
// buf (t+2)%3 -- all distinct; the stage target's old readers (PV(t-1))
// passed this iter's barrier.  21 x 3-phase unroll keeps indices literal.
// Sync: per-wave vmcnt(0) + barrier per phase (round-6-validated); last
// staging is tile 63 at t=61, drained at t=62's top -> nothing in flight
// at s_endpgm.
__global__ __launch_bounds__(256, 3) void attn_kernel(const ushort_t* __restrict__ Qh,
                                                      const ushort_t* __restrict__ Kh,
                                                      const ushort_t* __restrict__ Vt,
                                                      float* __restrict__ out) {
  const int bh = blockIdx.y;
  const int b = bh / NH, head = bh - b * NH;
  const int t = threadIdx.x, w = t >> 6, lane = t & 63;
  const int g = lane >> 4, qc = lane & 15;
  const ushort_t* Qb = Qh + (size_t)bh * SEQ * 64;
  const ushort_t* Kb = Kh + (size_t)bh * SEQ * 64;
  const ushort_t* Vb = Vt + (size_t)bh * 64 * SEQ;
  const int q0 = blockIdx.x * 128 + w * 32;

  __shared__ ushort_t Kls[3][4096];  // [buf][64 krow x 64 d], (r&7)-swizzled 16B chunks
  __shared__ ushort_t Vls[3][4096];  // [buf][64 d x 64 k],   (r&7)-swizzled 16B chunks

  int jr[2], jc[2];
#pragma unroll
  for (int i = 0; i < 2; ++i) {
    int j = w * 128 + i * 64 + lane;
    jr[i] = j >> 3;
    jc[i] = (j & 7) ^ (jr[i] & 7);
  }

  bfrag qv[2][2];
#pragma unroll
  for (int qf = 0; qf < 2; ++qf)
#pragma unroll
    for (int dd = 0; dd < 2; ++dd)
      qv[qf][dd] = *(const bfrag*)&Qb[(size_t)(q0 + qf * 16 + qc) * 64 + dd * 32 + g * 8];

  f32x4 o[2][4];
  f32x4 lacc[2];
#pragma unroll
  for (int qf = 0; qf < 2; ++qf) {
    lacc[qf] = zero4();
#pragma unroll
    for (int dt = 0; dt < 4; ++dt) o[qf][dt] = zero4();
  }
  bfrag ones;
#pragma unroll
  for (int j = 0; j < 8; ++j) ones[j] = (__bf16)1.0f;

  // prologue: stage tiles 0,1; compute QK(0) -> stA
  stage_tile(Kb, Vb, &Kls[0][0], &Vls[0][0], 0, jr, jc, w);
  stage_tile(Kb, Vb, &Kls[1][0], &Vls[1][0], 64, jr, jc, w);
  f32x4 stA[2][4], stB[2][4];
  WAIT_VMCNT4();   // tile 0's 4 DMAs landed (FIFO); tile 1's may be in flight
  __syncthreads(); // ...for all waves
  qk_tile(&Kls[0][0], qv, stA, g, qc);

  for (int tt = 0; tt < 21; ++tt) {
    const int t0 = tt * 3;
    // ---- phase 1 (t = t0): K[buf1]=t0+1, V[buf0]=t0, stage t0+2 -> buf2 ----
    WAIT_VMCNT0();
    __syncthreads();
    stage_tile(Kb, Vb, &Kls[2][0], &Vls[2][0], (t0 + 2) * 64, jr, jc, w);
    qk_tile(&Kls[1][0], qv, stB, g, qc);
    sm_pv_tile(&Vls[0][0], stA, o, lacc, ones, g, qc);
    // ---- phase 2 (t = t0+1): K[buf2]=t0+2, V[buf1]=t0+1, stage t0+3 -> buf0 ----
    WAIT_VMCNT0();
    __syncthreads();
    stage_tile(Kb, Vb, &Kls[0][0], &Vls[0][0], (t0 + 3) * 64, jr, jc, w);
    qk_tile(&Kls[2][0], qv, stA, g, qc);
    sm_pv_tile(&Vls[1][0], stB, o, lacc, ones, g, qc);
    // ---- phase 3 (t = t0+2): K[buf0]=t0+3, V[buf2]=t0+2, stage t0+4 -> buf1 ----
    WAIT_VMCNT0();
    __syncthreads();
    if (tt < 20)
      stage_tile(Kb, Vb, &Kls[1][0], &Vls[1][0], (t0 + 4) * 64, jr, jc, w);
    qk_tile(&Kls[0][0], qv, stB, g, qc);
    sm_pv_tile(&Vls[2][0], stA, o, lacc, ones, g, qc);
    // backedge: stB (tile t0+3) becomes next group's stA
#pragma unroll
    for (int qf = 0; qf < 2; ++qf)
#pragma unroll
      for (int s = 0; s < 4; ++s) stA[qf][s] = stB[qf][s];
  }

  // epilogue tile 63: everything staged & drained (last stage t=61, drained
  // at t=62's vmcnt(0)); V tile 63 sits in buf0.  No DMA in flight.
  sm_pv_tile(&Vls[0][0], stA, o, lacc, ones, g, qc);

  // output: O^T layout row d = dt*16+4g+i, col q = qc; l identical in every reg
#pragma unroll
  for (int qf = 0; qf < 2; ++qf) {
    float inv = 1.0f / lacc[qf][0];
    int qrow = q0 + qf * 16 + qc;
    float* orow = out + (size_t)(b * SEQ + qrow) * HID + head * 64;
#pragma unroll
    for (int dt = 0; dt < 4; ++dt) {
      float4 vv;
      vv.x = o[qf][dt][0] * inv; vv.y = o[qf][dt][1] * inv;
      vv.z = o[qf][dt][2] * inv; vv.w = o[qf][dt][3] * inv;
      *(float4*)(orow + dt * 16 + 4 * g) = vv;
    }
  }
}

// ---------------------------------------------------------------- launch
extern "C" void kernel_launch(void* const* d_in, const int* in_sizes, int n_in,
                              void* d_out, int out_size, void* d_ws, size_t ws_size,
                              hipStream_t stream) {
  (void)in_sizes; (void)n_in; (void)out_size; (void)ws_size;
  const float* hs = (const float*)d_in[0];
  const float* Wq = (const float*)d_in[1];
  const float* bq = (const float*)d_in[2];
  const float* Wk = (const float*)d_in[3];
  const float* bk = (const float*)d_in[4];
  const float* Wv = (const float*)d_in[5];
  const float* bv = (const float*)d_in[6];
  float* out = (float*)d_out;

  char* ws = (char*)d_ws;
  ushort_t* Abf = (ushort_t*)ws;                               // 12582912 B
  ushort_t* Wt  = (ushort_t*)(ws + 12582912);                  //  3538944 B
  ushort_t* Qh  = (ushort_t*)(ws + 12582912 + 3538944);        // 12582912 B
  ushort_t* Kh  = Qh + 6291456;
  ushort_t* Vt  = Kh + 6291456;

  cvt_hidden<<<6144, 256, 0, stream>>>(hs, Abf);
  transpose_w<<<dim3(12, 12, 3), 256, 0, stream>>>(Wq, Wk, Wv, Wt);
  qkv_gemm<<<dim3(64, 6, 3), 256, 0, stream>>>(Abf, Wt, bq, bk, bv, Qh, Kh, Vt);
  attn_kernel<<<dim3(32, 24), 256, 0, stream>>>(Qh, Kh, Vt, out);
}